// Round 1
// 2134.180 us; speedup vs baseline: 1.6309x; 1.6309x over previous
//
#include <hip/hip_runtime.h>
#include <hip/hip_bf16.h>

#define B_  128
#define T_  512
#define HID 512     // H = I = 512
#define NG  1536    // 3H
#define CSTRIDE 16  // sync-slot padding: 16 uints = 64B

// ---- sync buffer layout (uints) ----
// gcnt(t)  : slow-mode device step counter        [t*CSTRIDE]
// flags    : fast-mode per-(step,xcd,slice) flag  [FLAG0 + ((t*8+x)<<5) + kc]
// mem(x)   : XCD membership count                 [MEM0 + x*CSTRIDE]
// init     : one-time registration barrier        [INIT0]
#define GCNT(t)  ((t)*CSTRIDE)
#define FLAG0    (T_*CSTRIDE)
#define MEM0     (T_*CSTRIDE + T_*8*32)
#define INIT0    (MEM0 + 8*CSTRIDE)
#define SYNC_U32 (INIT0 + CSTRIDE)

typedef __attribute__((ext_vector_type(8))) short bf16x8;
typedef __attribute__((ext_vector_type(4))) float f32x4;
typedef unsigned int uint;

__device__ __forceinline__ float bf2f(unsigned short h) {
  union { unsigned u; float f; } c; c.u = ((unsigned)h) << 16; return c.f;
}
__device__ __forceinline__ unsigned short f2bf_rn(float f) {
  union { float f; unsigned u; } c; c.f = f;
  return (unsigned short)((c.u + 0x7FFFu + ((c.u >> 16) & 1u)) >> 16);
}
// split fp32 -> hi (truncated bf16) + lo (rn bf16 of residual); hi+lo ~ fp32
__device__ __forceinline__ void split1(float f, short& hi, short& lo) {
  union { float f; unsigned u; } c; c.f = f;
  unsigned short h = (unsigned short)(c.u >> 16);
  float r = f - bf2f(h);
  hi = (short)h; lo = (short)f2bf_rn(r);
}
__device__ __forceinline__ void split8(float4 a, float4 b, bf16x8& hi, bf16x8& lo) {
  float v[8] = {a.x,a.y,a.z,a.w,b.x,b.y,b.z,b.w};
  #pragma unroll
  for (int i = 0; i < 8; ++i) { short h,l; split1(v[i],h,l); hi[i]=h; lo[i]=l; }
}
__device__ __forceinline__ uint packh(float f) {
  short hi, lo; split1(f, hi, lo);
  return (((uint)(unsigned short)hi) << 16) | (uint)(unsigned short)lo;
}
__device__ __forceinline__ float unpackh(uint u) {
  return bf2f((unsigned short)(u >> 16)) + bf2f((unsigned short)(u & 0xFFFFu));
}

__device__ __forceinline__ uint aload_rlx(const uint* p) {
  return __hip_atomic_load(p, __ATOMIC_RELAXED, __HIP_MEMORY_SCOPE_AGENT);
}

// ---------------------------------------------------------------------------
// Kernel 0: pack h0 (fp32) into parity-1 packed buffer
// ---------------------------------------------------------------------------
__global__ void h0_pack(const float* __restrict__ h0, uint* __restrict__ hbuf) {
  int i = blockIdx.x * 256 + threadIdx.x;        // 65536 threads
  hbuf[65536 + i] = packh(h0[i]);
}

// ---------------------------------------------------------------------------
// Kernel 1: x_lin[m][n] = sum_k x[m][k]*Wx[n][k] + bx[n]
// M=65536, N=1536, K=512.  WG = 128x128 tile (2x2 waves of 64x64).
// ---------------------------------------------------------------------------
template<bool WSF32>
__global__ __launch_bounds__(256) void xlin_kernel(const float* __restrict__ x,
                                                   const float* __restrict__ Wx,
                                                   const float* __restrict__ bx,
                                                   void* __restrict__ xlin) {
  const int lane = threadIdx.x & 63;
  const int w    = threadIdx.x >> 6;
  const int wm   = w & 1, wn = w >> 1;
  const int quad = lane >> 4, l16 = lane & 15;
  const long m0  = (long)blockIdx.y * 128;
  const int  n0  = blockIdx.x * 128;

  f32x4 acc[4][4];
  #pragma unroll
  for (int i = 0; i < 4; ++i)
    #pragma unroll
    for (int j = 0; j < 4; ++j) acc[i][j] = (f32x4){0.f,0.f,0.f,0.f};

  for (int kk = 0; kk < 16; ++kk) {
    const int kq = kk*32 + quad*8;
    bf16x8 ahi[4], alo[4], bhi[4], blo[4];
    #pragma unroll
    for (int i = 0; i < 4; ++i) {
      const float* p = x + (m0 + wm*64 + i*16 + l16) * HID + kq;
      float4 f0 = ((const float4*)p)[0], f1 = ((const float4*)p)[1];
      split8(f0, f1, ahi[i], alo[i]);
      const float* q = Wx + (long)(n0 + wn*64 + i*16 + l16) * HID + kq;
      float4 g0 = ((const float4*)q)[0], g1 = ((const float4*)q)[1];
      split8(g0, g1, bhi[i], blo[i]);
    }
    #pragma unroll
    for (int i = 0; i < 4; ++i)
      #pragma unroll
      for (int j = 0; j < 4; ++j) {
        acc[i][j] = __builtin_amdgcn_mfma_f32_16x16x32_bf16(ahi[i], bhi[j], acc[i][j], 0, 0, 0);
        acc[i][j] = __builtin_amdgcn_mfma_f32_16x16x32_bf16(ahi[i], blo[j], acc[i][j], 0, 0, 0);
        acc[i][j] = __builtin_amdgcn_mfma_f32_16x16x32_bf16(alo[i], bhi[j], acc[i][j], 0, 0, 0);
      }
  }
  #pragma unroll
  for (int i = 0; i < 4; ++i) {
    #pragma unroll
    for (int j = 0; j < 4; ++j) {
      const int n = n0 + wn*64 + j*16 + l16;
      const float bias = bx[n];
      #pragma unroll
      for (int r = 0; r < 4; ++r) {
        const long m = m0 + wm*64 + i*16 + quad*4 + r;
        const float v = acc[i][j][r] + bias;
        if (WSF32) ((float*)xlin)[m * NG + n] = v;
        else       ((unsigned short*)xlin)[m * NG + n] = f2bf_rn(v);
      }
    }
  }
}

// ---------------------------------------------------------------------------
// Kernel 2: persistent GRU recurrence, XCD-LOCAL batch groups.
//
// Key fact: batches never interact (h_new[b,:] depends only on h[b,:]).
// So pin batch group g (16 batches) to XCD g via runtime XCC_ID discovery:
//  - producer set == consumer set == the 32 WGs on that XCD
//  - h stores stay dirty in the XCD-local L2 (plain write-through stores)
//  - h loads bypass L1 with sc0 -> hit local L2 (fresh, ~200 cy)
//  - per-step barrier = 32 plain flag words in local L2 (store after the
//    store-draining __syncthreads; per-wave sc0 poll on the consume side)
//  - NO wbl2 / NO inv / NO LLC atomics in the main loop at all
// Fallback (distribution unbalanced): device-scope release/acquire barrier —
// slow but correct under any WG->XCD mapping.
// ---------------------------------------------------------------------------
template<bool WSF32>
__global__ __launch_bounds__(256, 1) void gru_rec(const void* __restrict__ xlin,
                                                  const float* __restrict__ Wh,
                                                  uint* __restrict__ hbuf,
                                                  uint* __restrict__ sync,
                                                  float* __restrict__ out) {
  __shared__ float red[3][4][16][17];   // [gate][wave][b][k] (+1 pad: kills 4-way bank conflict)
  __shared__ int sh_xcd, sh_cb, sh_kc;
  __shared__ uint sh_fast;
  const int tid  = threadIdx.x;
  const int lane = tid & 63;
  const int w    = tid >> 6;
  const int quad = lane >> 4, l16 = lane & 15;

  // ---- one-time: XCD discovery + balanced check ----
  if (tid == 0) {
    uint id;
    __asm__ volatile("s_getreg_b32 %0, hwreg(HW_REG_XCC_ID, 0, 32)" : "=s"(id));
    const int xcd = (int)(id & 7u);
    uint xr = __hip_atomic_fetch_add(&sync[MEM0 + xcd*CSTRIDE], 1u,
                                     __ATOMIC_RELAXED, __HIP_MEMORY_SCOPE_AGENT);
    uint* ic = &sync[INIT0];
    uint gr = __hip_atomic_fetch_add(ic, 1u, __ATOMIC_ACQ_REL, __HIP_MEMORY_SCOPE_AGENT);
    while (aload_rlx(ic) < 256u) __builtin_amdgcn_s_sleep(1);
    (void)__hip_atomic_load(ic, __ATOMIC_ACQUIRE, __HIP_MEMORY_SCOPE_AGENT);
    bool bal = true;
    #pragma unroll
    for (int x = 0; x < 8; ++x)
      bal = bal && (aload_rlx(&sync[MEM0 + x*CSTRIDE]) == 32u);
    sh_xcd  = xcd;
    sh_fast = bal ? 1u : 0u;
    sh_cb   = bal ? xcd     : (int)(gr >> 5);   // batch group
    sh_kc   = bal ? (int)xr : (int)(gr & 31u);  // neuron slice
  }
  __syncthreads();
  const int  xcd   = sh_xcd;
  const bool fastm = (sh_fast != 0u);
  const int  cb    = sh_cb;
  const int  kc    = sh_kc;

  // ---- Wh fragments resident (split-bf16, 3-term) ----
  bf16x8 Bhi[3][4], Blo[3][4];
  #pragma unroll
  for (int g = 0; g < 3; ++g)
    #pragma unroll
    for (int kk = 0; kk < 4; ++kk) {
      const float* p = Wh + (long)(g*HID + kc*16 + l16) * HID + w*128 + kk*32 + quad*8;
      float4 f0 = ((const float4*)p)[0], f1 = ((const float4*)p)[1];
      split8(f0, f1, Bhi[g][kk], Blo[g][kk]);
    }

  const int bb   = tid >> 4;            // 0..15 local batch (gates phase)
  const int kk_  = tid & 15;            // 0..15 local neuron (gates phase)
  const int brow = cb*16 + bb;          // global batch
  const int ncol = kc*16 + kk_;         // global neuron
  float* yout = out;
  float* hfin = out + (long)B_ * T_ * HID;

  uint* const hb0 = hbuf;
  uint* const hb1 = hbuf + 65536;

  for (int t = 0; t < T_; ++t) {
    // --- x_lin prefetch: independent of h, issue BEFORE the wait ---
    float xz, xr, xn;
    {
      const long mrow = (long)brow * T_ + t;
      if (WSF32) {
        const float* xp = (const float*)xlin + mrow * NG + ncol;
        xz = xp[0]; xr = xp[HID]; xn = xp[2*HID];
      } else {
        const unsigned short* xp = (const unsigned short*)xlin + mrow * NG + ncol;
        xz = bf2f(xp[0]); xr = bf2f(xp[HID]); xn = bf2f(xp[2*HID]);
      }
    }

    // --- consume-side wait for step t-1 ---
    if (t > 0) {
      if (fastm) {
        // per-wave poll of 32 XCD-local flag words (L2-resident, sc0)
        const uint* fp = &sync[FLAG0 + (((t-1)*8 + xcd) << 5) + (lane & 31)];
        while (!__all(aload_rlx(fp) != 0u)) __builtin_amdgcn_s_sleep(1);
      } else {
        if (tid == 0) {
          uint* gp = &sync[GCNT(t-1)];
          while (aload_rlx(gp) < 256u) __builtin_amdgcn_s_sleep(1);
          (void)__hip_atomic_load(gp, __ATOMIC_ACQUIRE, __HIP_MEMORY_SCOPE_AGENT);
        }
        __syncthreads();
      }
    }

    const uint* rb = ((t + 1) & 1) ? hb1 : hb0;
    uint*       wb = (t & 1)       ? hb1 : hb0;

    // --- h loads: sc0 (L1-bypass) -> fresh from XCD-local L2 ---
    const uint* hp_ = rb + (cb*16 + l16)*HID + w*128 + quad*8;
    uint4 u0,u1,u2,u3,u4,u5,u6,u7;
    asm volatile(
      "global_load_dwordx4 %0, %8, off sc0\n\t"
      "global_load_dwordx4 %1, %8, off offset:16 sc0\n\t"
      "global_load_dwordx4 %2, %8, off offset:128 sc0\n\t"
      "global_load_dwordx4 %3, %8, off offset:144 sc0\n\t"
      "global_load_dwordx4 %4, %8, off offset:256 sc0\n\t"
      "global_load_dwordx4 %5, %8, off offset:272 sc0\n\t"
      "global_load_dwordx4 %6, %8, off offset:384 sc0\n\t"
      "global_load_dwordx4 %7, %8, off offset:400 sc0\n\t"
      "s_waitcnt vmcnt(0)"
      : "=&v"(u0), "=&v"(u1), "=&v"(u2), "=&v"(u3),
        "=&v"(u4), "=&v"(u5), "=&v"(u6), "=&v"(u7)
      : "v"(hp_)
      : "memory");
    const uint hpu = __hip_atomic_load(rb + brow*HID + ncol,
                                       __ATOMIC_RELAXED, __HIP_MEMORY_SCOPE_AGENT);

    // --- GEMM: wave covers K-slice [w*128, w*128+128) ---
    const uint4 uu[4][2] = {{u0,u1},{u2,u3},{u4,u5},{u6,u7}};
    f32x4 acc[3] = { (f32x4){0,0,0,0}, (f32x4){0,0,0,0}, (f32x4){0,0,0,0} };
    #pragma unroll
    for (int kk = 0; kk < 4; ++kk) {
      bf16x8 ah, al;
      #pragma unroll
      for (int i = 0; i < 4; ++i) {
        uint v0 = ((const uint*)&uu[kk][0])[i];
        uint v1 = ((const uint*)&uu[kk][1])[i];
        ah[i]   = (short)(v0 >> 16); al[i]   = (short)(v0 & 0xFFFFu);
        ah[i+4] = (short)(v1 >> 16); al[i+4] = (short)(v1 & 0xFFFFu);
      }
      #pragma unroll
      for (int g = 0; g < 3; ++g) {
        acc[g] = __builtin_amdgcn_mfma_f32_16x16x32_bf16(ah, Bhi[g][kk], acc[g], 0, 0, 0);
        acc[g] = __builtin_amdgcn_mfma_f32_16x16x32_bf16(ah, Blo[g][kk], acc[g], 0, 0, 0);
        acc[g] = __builtin_amdgcn_mfma_f32_16x16x32_bf16(al, Bhi[g][kk], acc[g], 0, 0, 0);
      }
    }
    #pragma unroll
    for (int g = 0; g < 3; ++g)
      #pragma unroll
      for (int r = 0; r < 4; ++r)
        red[g][w][quad*4 + r][l16] = acc[g][r];

    const float hp = unpackh(hpu);

    __syncthreads();

    float az = 0.f, ar = 0.f, an = 0.f;
    #pragma unroll
    for (int ww = 0; ww < 4; ++ww) {
      az += red[0][ww][bb][kk_];
      ar += red[1][ww][bb][kk_];
      an += red[2][ww][bb][kk_];
    }
    const float z = 1.f / (1.f + __expf(-(az + xz)));
    const float r = 1.f / (1.f + __expf(-(ar + xr)));
    const float pre = xn + r * an;
    const float e2 = __expf(-2.f * pre);
    const float n = 2.f / (1.f + e2) - 1.f;          // tanh, inf-safe
    const float hn = (1.f - z) * n + z * hp;

    if (t < T_ - 1) {
      wb[brow*HID + ncol] = packh(hn);               // plain store -> own L2
    } else {
      hfin[brow*HID + ncol] = hn;
    }

    // __syncthreads drains every wave's h stores into L2 BEFORE the flag store
    __syncthreads();
    if (t < T_ - 1) {
      if (fastm) {
        if (tid == 0) sync[FLAG0 + ((t*8 + xcd) << 5) + kc] = 1u;  // local-L2 flag
      } else {
        if (tid == 0)
          __hip_atomic_fetch_add(&sync[GCNT(t)], 1u,
                                 __ATOMIC_RELEASE, __HIP_MEMORY_SCOPE_AGENT);
      }
    }

    // y store AFTER signaling: its HBM ack is off the critical path
    __builtin_nontemporal_store(hn, &yout[((long)brow * T_ + t) * HID + ncol]);
  }
}

// ---------------------------------------------------------------------------
extern "C" void kernel_launch(void* const* d_in, const int* in_sizes, int n_in,
                              void* d_out, int out_size, void* d_ws, size_t ws_size,
                              hipStream_t stream) {
  const float* x  = (const float*)d_in[0];
  const float* h0 = (const float*)d_in[1];
  const float* Wx = (const float*)d_in[2];
  const float* bx = (const float*)d_in[3];
  const float* Wh = (const float*)d_in[4];
  float* out = (float*)d_out;

  const size_t xlin_f32  = (size_t)B_ * T_ * NG * 4;   // 402,653,184
  const size_t xlin_bf16 = (size_t)B_ * T_ * NG * 2;   // 201,326,592
  const size_t hbuf_sz   = (size_t)2 * 65536 * 4;      // 512 KiB (packed uint)
  const size_t sync_sz   = (size_t)SYNC_U32 * 4;       // ~545 KiB

  const bool wsf32 = (ws_size >= xlin_f32 + hbuf_sz + sync_sz);
  const size_t xsz = wsf32 ? xlin_f32 : xlin_bf16;
  void* xlin = d_ws;
  uint* hbuf = (uint*)((char*)d_ws + xsz);
  uint* sync = (uint*)((char*)d_ws + xsz + hbuf_sz);

  hipMemsetAsync(sync, 0, sync_sz, stream);
  h0_pack<<<256, 256, 0, stream>>>(h0, hbuf);
  if (wsf32) {
    xlin_kernel<true ><<<dim3(12, 512), 256, 0, stream>>>(x, Wx, bx, xlin);
    gru_rec<true >    <<<256, 256, 0, stream>>>(xlin, Wh, hbuf, sync, out);
  } else {
    xlin_kernel<false><<<dim3(12, 512), 256, 0, stream>>>(x, Wx, bx, xlin);
    gru_rec<false>    <<<256, 256, 0, stream>>>(xlin, Wh, hbuf, sync, out);
  }
}

// Round 3
// 2022.181 us; speedup vs baseline: 1.7212x; 1.0554x over previous
//
#include <hip/hip_runtime.h>
#include <hip/hip_bf16.h>

#define B_  128
#define T_  512
#define HID 512     // H = I = 512
#define NG  1536    // 3H
#define CSTRIDE 16  // sync-slot padding: 16 uints = 64B

// ---- sync buffer layout (uints) ----
// gcnt(t)  : slow-mode device step counter            [t*CSTRIDE]
// flag     : fast-mode monotonic per-(xcd,kc) counter [FLAG0 + (xcd*32+kc)*CSTRIDE]
//            producer of (xcd,kc) stores t+1 after step t's h is drained to L2;
//            consumer at step t polls >= t.  No reset, only 16KB hot.
// mem(x)   : XCD membership count                     [MEM0 + x*CSTRIDE]
// init     : one-time registration barrier            [INIT0]
#define GCNT(t)  ((t)*CSTRIDE)
#define FLAG0    (T_*CSTRIDE)
#define MEM0     (FLAG0 + 256*CSTRIDE)
#define INIT0    (MEM0 + 8*CSTRIDE)
#define SYNC_U32 (INIT0 + CSTRIDE)

typedef __attribute__((ext_vector_type(8))) short bf16x8;
typedef __attribute__((ext_vector_type(4))) float f32x4;
typedef unsigned int uint;
typedef unsigned short u16;

// h buffer layout (u16): 2 parities x [128 rows][1024] where
// row = batch, cols 0..511 = hi bf16, cols 512..1023 = lo bf16.
// hi/lo split in SEPARATE halves of the row -> MFMA fragments load directly
// as dwordx4 (8 consecutive shorts), zero unpack VALU.
#define HROW 1024
#define HPAR 131072   // 128*1024 shorts per parity

__device__ __forceinline__ float bf2f(unsigned short h) {
  union { unsigned u; float f; } c; c.u = ((unsigned)h) << 16; return c.f;
}
__device__ __forceinline__ unsigned short f2bf_rn(float f) {
  union { float f; unsigned u; } c; c.f = f;
  return (unsigned short)((c.u + 0x7FFFu + ((c.u >> 16) & 1u)) >> 16);
}
// split fp32 -> hi (truncated bf16) + lo (rn bf16 of residual); hi+lo ~ fp32
__device__ __forceinline__ void split1(float f, short& hi, short& lo) {
  union { float f; unsigned u; } c; c.f = f;
  unsigned short h = (unsigned short)(c.u >> 16);
  float r = f - bf2f(h);
  hi = (short)h; lo = (short)f2bf_rn(r);
}
__device__ __forceinline__ void split8(float4 a, float4 b, bf16x8& hi, bf16x8& lo) {
  float v[8] = {a.x,a.y,a.z,a.w,b.x,b.y,b.z,b.w};
  #pragma unroll
  for (int i = 0; i < 8; ++i) { short h,l; split1(v[i],h,l); hi[i]=h; lo[i]=l; }
}

__device__ __forceinline__ uint aload_rlx(const uint* p) {
  return __hip_atomic_load(p, __ATOMIC_RELAXED, __HIP_MEMORY_SCOPE_AGENT);
}

// ---------------------------------------------------------------------------
// Kernel 0: split h0 (fp32) into parity-1 hi/lo buffer
// ---------------------------------------------------------------------------
__global__ void h0_pack(const float* __restrict__ h0, u16* __restrict__ hbuf) {
  int i = blockIdx.x * 256 + threadIdx.x;        // 65536 threads
  short hi, lo; split1(h0[i], hi, lo);
  u16* p = hbuf + HPAR + (i >> 9) * HROW + (i & 511);
  p[0]   = (u16)hi;
  p[512] = (u16)lo;
}

// ---------------------------------------------------------------------------
// Kernel 1: x_lin[m][n] = sum_k x[m][k]*Wx[n][k] + bx[n]
// M=65536, N=1536, K=512.  WG = 128x128 tile (2x2 waves of 64x64).
// ---------------------------------------------------------------------------
template<bool WSF32>
__global__ __launch_bounds__(256) void xlin_kernel(const float* __restrict__ x,
                                                   const float* __restrict__ Wx,
                                                   const float* __restrict__ bx,
                                                   void* __restrict__ xlin) {
  const int lane = threadIdx.x & 63;
  const int w    = threadIdx.x >> 6;
  const int wm   = w & 1, wn = w >> 1;
  const int quad = lane >> 4, l16 = lane & 15;
  const long m0  = (long)blockIdx.y * 128;
  const int  n0  = blockIdx.x * 128;

  f32x4 acc[4][4];
  #pragma unroll
  for (int i = 0; i < 4; ++i)
    #pragma unroll
    for (int j = 0; j < 4; ++j) acc[i][j] = (f32x4){0.f,0.f,0.f,0.f};

  for (int kk = 0; kk < 16; ++kk) {
    const int kq = kk*32 + quad*8;
    bf16x8 ahi[4], alo[4], bhi[4], blo[4];
    #pragma unroll
    for (int i = 0; i < 4; ++i) {
      const float* p = x + (m0 + wm*64 + i*16 + l16) * HID + kq;
      float4 f0 = ((const float4*)p)[0], f1 = ((const float4*)p)[1];
      split8(f0, f1, ahi[i], alo[i]);
      const float* q = Wx + (long)(n0 + wn*64 + i*16 + l16) * HID + kq;
      float4 g0 = ((const float4*)q)[0], g1 = ((const float4*)q)[1];
      split8(g0, g1, bhi[i], blo[i]);
    }
    #pragma unroll
    for (int i = 0; i < 4; ++i)
      #pragma unroll
      for (int j = 0; j < 4; ++j) {
        acc[i][j] = __builtin_amdgcn_mfma_f32_16x16x32_bf16(ahi[i], bhi[j], acc[i][j], 0, 0, 0);
        acc[i][j] = __builtin_amdgcn_mfma_f32_16x16x32_bf16(ahi[i], blo[j], acc[i][j], 0, 0, 0);
        acc[i][j] = __builtin_amdgcn_mfma_f32_16x16x32_bf16(alo[i], bhi[j], acc[i][j], 0, 0, 0);
      }
  }
  #pragma unroll
  for (int i = 0; i < 4; ++i) {
    #pragma unroll
    for (int j = 0; j < 4; ++j) {
      const int n = n0 + wn*64 + j*16 + l16;
      const float bias = bx[n];
      #pragma unroll
      for (int r = 0; r < 4; ++r) {
        const long m = m0 + wm*64 + i*16 + quad*4 + r;
        const float v = acc[i][j][r] + bias;
        if (WSF32) ((float*)xlin)[m * NG + n] = v;
        else       ((unsigned short*)xlin)[m * NG + n] = f2bf_rn(v);
      }
    }
  }
}

// ---------------------------------------------------------------------------
// Kernel 2: persistent GRU recurrence, XCD-local batch groups.
//
// Sync topology proven in round 1 (XCD-local flags, no wbl2/inv/LLC atomics
// in the main loop).  This version removes hidden HBM latency from the
// per-step critical path (vmcnt is FIFO -> any poll wait drains ALL older
// vmem ops):
//  - xlin loads batched 8 steps into registers (HBM latency paid 1x/8 steps)
//  - y stores buffered 8 steps in registers, flushed after the flag signal
//  - h stored as separate hi/lo bf16 halves -> fragments load directly,
//    no unpack VALU in the MFMA loop
//  - monotonic flag words (flag = t+1, poll >= t): 16KB hot, 64B/slot
//
// Safety audit: step t reads parity (t+1)&1; step t+1 writes that parity,
// but only after polling all flags >= t+1, and each WG signals t+1 only
// AFTER its step-t reads completed (vmcnt(0) in the load asm precedes the
// dependent gate math; signal follows __syncthreads).  No overwrite race.
// ---------------------------------------------------------------------------
template<bool WSF32>
__global__ __launch_bounds__(256, 1) void gru_rec(const void* __restrict__ xlin,
                                                  const float* __restrict__ Wh,
                                                  u16* __restrict__ hbuf,
                                                  uint* __restrict__ sync,
                                                  float* __restrict__ out) {
  __shared__ float red[3][4][16][17];   // [gate][wave][b][k] (+1 pad)
  __shared__ int sh_xcd, sh_cb, sh_kc;
  __shared__ uint sh_fast;
  const int tid  = threadIdx.x;
  const int lane = tid & 63;
  const int w    = tid >> 6;
  const int quad = lane >> 4, l16 = lane & 15;

  // ---- one-time: XCD discovery + balanced check ----
  if (tid == 0) {
    uint id;
    __asm__ volatile("s_getreg_b32 %0, hwreg(HW_REG_XCC_ID, 0, 32)" : "=s"(id));
    const int xcd = (int)(id & 7u);
    uint xr = __hip_atomic_fetch_add(&sync[MEM0 + xcd*CSTRIDE], 1u,
                                     __ATOMIC_RELAXED, __HIP_MEMORY_SCOPE_AGENT);
    uint* ic = &sync[INIT0];
    uint gr = __hip_atomic_fetch_add(ic, 1u, __ATOMIC_ACQ_REL, __HIP_MEMORY_SCOPE_AGENT);
    while (aload_rlx(ic) < 256u) __builtin_amdgcn_s_sleep(1);
    (void)__hip_atomic_load(ic, __ATOMIC_ACQUIRE, __HIP_MEMORY_SCOPE_AGENT);
    bool bal = true;
    #pragma unroll
    for (int x = 0; x < 8; ++x)
      bal = bal && (aload_rlx(&sync[MEM0 + x*CSTRIDE]) == 32u);
    sh_xcd  = xcd;
    sh_fast = bal ? 1u : 0u;
    sh_cb   = bal ? xcd     : (int)(gr >> 5);   // batch group
    sh_kc   = bal ? (int)xr : (int)(gr & 31u);  // neuron slice
  }
  __syncthreads();
  const int  xcd   = sh_xcd;
  const bool fastm = (sh_fast != 0u);
  const int  cb    = sh_cb;
  const int  kc    = sh_kc;

  // ---- Wh fragments resident (split-bf16, 3-term) ----
  bf16x8 Bhi[3][4], Blo[3][4];
  #pragma unroll
  for (int g = 0; g < 3; ++g)
    #pragma unroll
    for (int kk = 0; kk < 4; ++kk) {
      const float* p = Wh + (long)(g*HID + kc*16 + l16) * HID + w*128 + kk*32 + quad*8;
      float4 f0 = ((const float4*)p)[0], f1 = ((const float4*)p)[1];
      split8(f0, f1, Bhi[g][kk], Blo[g][kk]);
    }

  const int bb   = tid >> 4;            // 0..15 local batch (gates phase)
  const int kk_  = tid & 15;            // 0..15 local neuron (gates phase)
  const int brow = cb*16 + bb;          // global batch
  const int ncol = kc*16 + kk_;         // global neuron
  float* yout = out;
  float* hfin = out + (long)B_ * T_ * HID;

  // per-lane fragment base offset (shorts), parity added per step
  const int fragoff = (cb*16 + l16)*HROW + w*128 + quad*8;
  const int hpoff   = brow*HROW + ncol;

  float xq[8][3];   // 8-step xlin register queue (statically indexed)
  float yq[8];      // 8-step y output queue

  // preload block 0
  {
    const long base = (long)brow * T_;
    #pragma unroll
    for (int q = 0; q < 8; ++q) {
      if (WSF32) {
        const float* xp = (const float*)xlin + (base + q) * NG + ncol;
        xq[q][0] = xp[0]; xq[q][1] = xp[HID]; xq[q][2] = xp[2*HID];
      } else {
        const unsigned short* xp = (const unsigned short*)xlin + (base + q) * NG + ncol;
        xq[q][0] = bf2f(xp[0]); xq[q][1] = bf2f(xp[HID]); xq[q][2] = bf2f(xp[2*HID]);
      }
    }
  }

  for (int tb = 0; tb < T_/8; ++tb) {
    #pragma unroll
    for (int ts = 0; ts < 8; ++ts) {
      const int t = tb*8 + ts;
      const float xz = xq[ts][0], xr = xq[ts][1], xn = xq[ts][2];

      // --- consume-side wait for step t-1 ---
      if (t > 0) {
        if (fastm) {
          const uint* fp = &sync[FLAG0 + (xcd*32 + (lane & 31))*CSTRIDE];
          while (!__all(aload_rlx(fp) >= (uint)t)) __builtin_amdgcn_s_sleep(1);
        } else {
          if (tid == 0) {
            uint* gp = &sync[GCNT(t-1)];
            while (aload_rlx(gp) < 256u) __builtin_amdgcn_s_sleep(1);
            (void)__hip_atomic_load(gp, __ATOMIC_ACQUIRE, __HIP_MEMORY_SCOPE_AGENT);
          }
          __syncthreads();
        }
      }

      const u16* rb = hbuf + ((t + 1) & 1) * HPAR;
      u16*       wb = hbuf + (t & 1)       * HPAR;

      // --- h loads: sc0 (L1-bypass) -> fresh from XCD-local L2.
      // hi fragments at +0, lo fragments at +1024B; hp (own prev h) folded in.
      const u16* hp_ = rb + fragoff;
      const u16* hpp = rb + hpoff;
      uint4 u0,u1,u2,u3,u4,u5,u6,u7; uint hu, lu;
      asm volatile(
        "global_load_dwordx4 %0, %10, off sc0\n\t"
        "global_load_dwordx4 %1, %10, off offset:64 sc0\n\t"
        "global_load_dwordx4 %2, %10, off offset:128 sc0\n\t"
        "global_load_dwordx4 %3, %10, off offset:192 sc0\n\t"
        "global_load_dwordx4 %4, %10, off offset:1024 sc0\n\t"
        "global_load_dwordx4 %5, %10, off offset:1088 sc0\n\t"
        "global_load_dwordx4 %6, %10, off offset:1152 sc0\n\t"
        "global_load_dwordx4 %7, %10, off offset:1216 sc0\n\t"
        "global_load_ushort %8, %11, off sc0\n\t"
        "global_load_ushort %9, %11, off offset:1024 sc0\n\t"
        "s_waitcnt vmcnt(0)"
        : "=&v"(u0), "=&v"(u1), "=&v"(u2), "=&v"(u3),
          "=&v"(u4), "=&v"(u5), "=&v"(u6), "=&v"(u7),
          "=&v"(hu), "=&v"(lu)
        : "v"(hp_), "v"(hpp)
        : "memory");

      // --- GEMM: wave covers K-slice [w*128, w*128+128), zero unpack ---
      f32x4 acc[3] = { (f32x4){0,0,0,0}, (f32x4){0,0,0,0}, (f32x4){0,0,0,0} };
      {
        const bf16x8 ah0 = *(const bf16x8*)&u0, al0 = *(const bf16x8*)&u4;
        const bf16x8 ah1 = *(const bf16x8*)&u1, al1 = *(const bf16x8*)&u5;
        const bf16x8 ah2 = *(const bf16x8*)&u2, al2 = *(const bf16x8*)&u6;
        const bf16x8 ah3 = *(const bf16x8*)&u3, al3 = *(const bf16x8*)&u7;
        const bf16x8 AH[4] = {ah0, ah1, ah2, ah3};
        const bf16x8 AL[4] = {al0, al1, al2, al3};
        #pragma unroll
        for (int kk = 0; kk < 4; ++kk) {
          #pragma unroll
          for (int g = 0; g < 3; ++g) {
            acc[g] = __builtin_amdgcn_mfma_f32_16x16x32_bf16(AH[kk], Bhi[g][kk], acc[g], 0, 0, 0);
            acc[g] = __builtin_amdgcn_mfma_f32_16x16x32_bf16(AH[kk], Blo[g][kk], acc[g], 0, 0, 0);
            acc[g] = __builtin_amdgcn_mfma_f32_16x16x32_bf16(AL[kk], Bhi[g][kk], acc[g], 0, 0, 0);
          }
        }
      }
      #pragma unroll
      for (int g = 0; g < 3; ++g)
        #pragma unroll
        for (int r = 0; r < 4; ++r)
          red[g][w][quad*4 + r][l16] = acc[g][r];

      const float hp = bf2f((unsigned short)hu) + bf2f((unsigned short)lu);

      __syncthreads();

      float az = 0.f, ar = 0.f, an = 0.f;
      #pragma unroll
      for (int ww = 0; ww < 4; ++ww) {
        az += red[0][ww][bb][kk_];
        ar += red[1][ww][bb][kk_];
        an += red[2][ww][bb][kk_];
      }
      const float z = 1.f / (1.f + __expf(-(az + xz)));
      const float r = 1.f / (1.f + __expf(-(ar + xr)));
      const float pre = xn + r * an;
      const float e2 = __expf(-2.f * pre);
      const float n = 2.f / (1.f + e2) - 1.f;          // tanh, inf-safe
      const float hn = (1.f - z) * n + z * hp;
      yq[ts] = hn;

      if (t < T_ - 1) {
        short shi, slo; split1(hn, shi, slo);
        u16* wp = wb + hpoff;
        wp[0]   = (u16)shi;                            // plain store -> own L2
        wp[512] = (u16)slo;
      } else {
        hfin[brow*HID + ncol] = hn;
      }

      // __syncthreads drains every wave's h stores into L2 BEFORE the flag
      __syncthreads();
      if (t < T_ - 1) {
        if (fastm) {
          if (tid == 0)
            sync[FLAG0 + (xcd*32 + kc)*CSTRIDE] = (uint)(t + 1);  // local-L2 flag
        } else {
          if (tid == 0)
            __hip_atomic_fetch_add(&sync[GCNT(t)], 1u,
                                   __ATOMIC_RELEASE, __HIP_MEMORY_SCOPE_AGENT);
        }
      }

      // --- block boundary: flush y queue, preload next xlin block.
      // These HBM ops drain at the NEXT block's first poll (1x per 8 steps)
      // instead of gating every step's poll (vmcnt FIFO).
      if (ts == 7) {
        #pragma unroll
        for (int q = 0; q < 8; ++q)
          __builtin_nontemporal_store(yq[q],
              &yout[((long)brow * T_ + tb*8 + q) * HID + ncol]);
        if (tb + 1 < T_/8) {
          const long base = (long)brow * T_ + (tb + 1)*8;
          #pragma unroll
          for (int q = 0; q < 8; ++q) {
            if (WSF32) {
              const float* xp = (const float*)xlin + (base + q) * NG + ncol;
              xq[q][0] = xp[0]; xq[q][1] = xp[HID]; xq[q][2] = xp[2*HID];
            } else {
              const unsigned short* xp = (const unsigned short*)xlin + (base + q) * NG + ncol;
              xq[q][0] = bf2f(xp[0]); xq[q][1] = bf2f(xp[HID]); xq[q][2] = bf2f(xp[2*HID]);
            }
          }
        }
      }
    }
  }
}

// ---------------------------------------------------------------------------
extern "C" void kernel_launch(void* const* d_in, const int* in_sizes, int n_in,
                              void* d_out, int out_size, void* d_ws, size_t ws_size,
                              hipStream_t stream) {
  const float* x  = (const float*)d_in[0];
  const float* h0 = (const float*)d_in[1];
  const float* Wx = (const float*)d_in[2];
  const float* bx = (const float*)d_in[3];
  const float* Wh = (const float*)d_in[4];
  float* out = (float*)d_out;

  const size_t xlin_f32  = (size_t)B_ * T_ * NG * 4;   // 402,653,184
  const size_t xlin_bf16 = (size_t)B_ * T_ * NG * 2;   // 201,326,592
  const size_t hbuf_sz   = (size_t)2 * HPAR * 2;       // 512 KiB (hi/lo u16)
  const size_t sync_sz   = (size_t)SYNC_U32 * 4;       // ~50 KiB

  const bool wsf32 = (ws_size >= xlin_f32 + hbuf_sz + sync_sz);
  const size_t xsz = wsf32 ? xlin_f32 : xlin_bf16;
  void* xlin = d_ws;
  u16*  hbuf = (u16*)((char*)d_ws + xsz);
  uint* sync = (uint*)((char*)d_ws + xsz + hbuf_sz);

  hipMemsetAsync(sync, 0, sync_sz, stream);
  h0_pack<<<256, 256, 0, stream>>>(h0, hbuf);
  if (wsf32) {
    xlin_kernel<true ><<<dim3(12, 512), 256, 0, stream>>>(x, Wx, bx, xlin);
    gru_rec<true >    <<<256, 256, 0, stream>>>(xlin, Wh, hbuf, sync, out);
  } else {
    xlin_kernel<false><<<dim3(12, 512), 256, 0, stream>>>(x, Wx, bx, xlin);
    gru_rec<false>    <<<256, 256, 0, stream>>>(xlin, Wh, hbuf, sync, out);
  }
}